// Round 1
// 1490.716 us; speedup vs baseline: 1.0136x; 1.0136x over previous
//
#include <hip/hip_runtime.h>
#include <cstdint>
#include <cstddef>

#define BATCH 64
#define SEQ   128
#define EMB   512
#define HID   1024
#define NCLS  10000
#define NG    4096      // 4*HID gate columns
#define NOP   10048     // padded output columns (314 * 32)
#define BH    (BATCH * HID)   // one h slot (elements)

typedef __attribute__((ext_vector_type(8))) short short8;
typedef __attribute__((ext_vector_type(4))) short short4v;
typedef __attribute__((ext_vector_type(4))) float floatx4;
typedef unsigned short u16;

// dynamic LDS: 128 KB W slice + red[2][64][33] fp32
#define LDS_W_U16  65536
#define LDS_BYTES  (131072 + 2*64*33*4)   // 147968

__device__ __forceinline__ u16 f2bf(float x) {
    union { float f; unsigned u; } v; v.f = x;
    unsigned r = v.u + 0x7fffu + ((v.u >> 16) & 1u);   // RNE
    return (u16)(r >> 16);
}
__device__ __forceinline__ float sigm(float x) { return 1.f / (1.f + __expf(-x)); }

__device__ __forceinline__ void wait_ge(unsigned* p, unsigned tgt) {
    while (__hip_atomic_load(p, __ATOMIC_RELAXED, __HIP_MEMORY_SCOPE_AGENT) < tgt)
        __builtin_amdgcn_s_sleep(4);
}

// ---------------------------------------------------------------------------
// Pack 4 gate matrices [K][1024] fp32 -> Wcat k-inner-8 bf16 layout:
//   element (k, col n) at dst[((k>>3)*NG + n)*8 + (k&7)],  n = unit*4 + gate.
// ---------------------------------------------------------------------------
__global__ void pack_gates(const float* __restrict__ s0, const float* __restrict__ s1,
                           const float* __restrict__ s2, const float* __restrict__ s3,
                           u16* __restrict__ dst, int kgroups, int kg_off) {
    int t = blockIdx.x * blockDim.x + threadIdx.x;
    if (t >= kgroups * HID) return;
    int u  = t & (HID - 1);
    int kg = t >> 10;
    u16* out = dst + ((size_t)(kg + kg_off) * NG + (size_t)u * 4) * 8;
#pragma unroll
    for (int g = 0; g < 4; ++g) {
        const float* s = (g == 0) ? s0 : (g == 1) ? s1 : (g == 2) ? s2 : s3;
        short8 v;
#pragma unroll
        for (int j = 0; j < 8; ++j)
            v[j] = (short)f2bf(s[(size_t)(kg * 8 + j) * HID + u]);
        *(short8*)(out + g * 8) = v;
    }
}

// W_out [1024][10000] fp32 -> padded k-inner-8 bf16 [(128)][10048][8]
__global__ void pack_wout(const float* __restrict__ src, u16* __restrict__ dst) {
    int t = blockIdx.x * blockDim.x + threadIdx.x;
    if (t >= 128 * NCLS) return;
    int n  = t % NCLS;
    int kg = t / NCLS;
    short8 v;
#pragma unroll
    for (int j = 0; j < 8; ++j)
        v[j] = (short)f2bf(src[(size_t)(kg * 8 + j) * NCLS + n]);
    *(short8*)(dst + ((size_t)kg * NOP + n) * 8) = v;
}

// E[s][b][:] = bf16(C[X[b][s]][:])   (E laid out [SEQ][BATCH][EMB])
__global__ void embed_k(const int* __restrict__ X, const float* __restrict__ C,
                        u16* __restrict__ E) {
    const int sb = blockIdx.x;             // s*64 + m
    const int s = sb >> 6, m = sb & 63;
    const int row = X[m * SEQ + s];
    const floatx4* src = (const floatx4*)(C + (size_t)row * EMB);
    u16* dst = E + (size_t)sb * EMB;
    const int t = threadIdx.x;             // 128 threads, 4 elems each
    floatx4 v = src[t];
    short4v o;
    o[0] = (short)f2bf(v[0]); o[1] = (short)f2bf(v[1]);
    o[2] = (short)f2bf(v[2]); o[3] = (short)f2bf(v[3]);
    *(short4v*)(dst + t * 4) = o;
}

// ---------------------------------------------------------------------------
// One LSTM step COMPUTE: A-fragments already prefetched into areg[] registers.
// 512 threads = 8 waves: w = km + 2*mw (2-way K x 4-way M).
// Wave (km,mw): rows mw*16..+15, 32 cols, k-half km. B from LDS.
// Epilogue: 1 thread per (m,u). h written via agent-scope relaxed atomic
// stores (sc1 write-through to L3 -> no dirty L2, L3 always fresh).
// ---------------------------------------------------------------------------
template<int CHH, bool WRITE_H>
__device__ __forceinline__ void step_compute(
    u16* __restrict__ WL, float (*red)[64][33],
    const short8 (&areg)[CHH],
    u16* __restrict__ ho, u16* __restrict__ Hout,
    float& c, float bF, float bI, float bC, float bO, int ub)
{
    const int tid = threadIdx.x;
    const int w = tid >> 6, l = tid & 63;
    const int ml = l & 15, q = l >> 4;
    const int km = w & 1, mw = w >> 1;

    floatx4 acc0 = {0.f, 0.f, 0.f, 0.f}, acc1 = {0.f, 0.f, 0.f, 0.f};

    // B base: original index ((k>>3)+q)*32 + ml with k = (km*CHH+ci)*32
    //   -> wb + ci*1024 u16 (compile-time immediate per unrolled ci)
    const u16* wb = WL + ((size_t)((km * CHH * 4 + q) * 32 + ml)) * 8;
#pragma unroll
    for (int ci = 0; ci < CHH; ++ci) {
        const u16* br = wb + (size_t)ci * 1024;
        short8 b0 = *(const short8*)br;
        short8 b1 = *(const short8*)(br + 128);
        acc0 = __builtin_amdgcn_mfma_f32_16x16x32_bf16(areg[ci], b0, acc0, 0, 0, 0);
        acc1 = __builtin_amdgcn_mfma_f32_16x16x32_bf16(areg[ci], b1, acc1, 0, 0, 0);
    }

#pragma unroll
    for (int r = 0; r < 4; ++r) {
        red[km][mw * 16 + q * 4 + r][ml]      = acc0[r];
        red[km][mw * 16 + q * 4 + r][16 + ml] = acc1[r];
    }
    __syncthreads();

    const int m = tid >> 3, u = tid & 7;
    const int nl = u * 4;
    const int ug = ub * 8 + u;
    float p0 = red[0][m][nl + 0] + red[1][m][nl + 0];
    float p1 = red[0][m][nl + 1] + red[1][m][nl + 1];
    float p2 = red[0][m][nl + 2] + red[1][m][nl + 2];
    float p3 = red[0][m][nl + 3] + red[1][m][nl + 3];
    float f = sigm(p0 + bF);
    float i = sigm(p1 + bI);
    float g = tanhf(p2 + bC);
    float o = sigm(p3 + bO);
    float cc = f * c + i * g;
    c = cc;
    u16 hb = f2bf(o * tanhf(cc));
    __hip_atomic_store(&ho[(size_t)m * HID + ug], hb,
                       __ATOMIC_RELAXED, __HIP_MEMORY_SCOPE_AGENT);
    if (WRITE_H)
        __hip_atomic_store(&Hout[(size_t)m * HID + ug], hb,
                           __ATOMIC_RELAXED, __HIP_MEMORY_SCOPE_AGENT);
}

// ---------------------------------------------------------------------------
// Persistent kernel. 256 blocks x 512 thr, 147968 B LDS -> 1 block/CU.
// Round-6 coherence design (validated): NO fences in the tick loop.
//   - h0/h1 are 129-slot per-tick chains; H is per-tick. A consumer's L2
//     can only acquire these lines via a fresh L3 fill.
//   - producers: sc1 write-through stores -> L3 always fresh, L2 never dirty.
//   - barrier arrivals spread over 16 cachelines (8 adds/line).
// THIS ROUND: explicit A-register prefetch with compile-time-resolved bases.
//   - per-wave A slice loaded into areg[CHH] (all loads in flight at once)
//   - loads issued as early as their gate allows:
//       L0: E-part issued BEFORE the bar0 poll (depends only on embed_k);
//           pollers moved to wave 1 (km=1, no outstanding loads -> their
//           per-wave vmcnt(0) poll drain cannot stall the prefetch).
//       L1: km=1 h1c loads issued after bar1 join (early signal); km=0 H
//           loads issued after hcnt join (late signal).
//   - joins use raw s_barrier (control-only; __syncthreads would emit
//     s_waitcnt vmcnt(0) and drain the in-flight prefetch).
// ---------------------------------------------------------------------------
struct PArgs {
    const u16 *E, *Wcat0, *Wcat1;
    u16 *H, *h0c, *h1c;     // h chains: 129 slots of [64][1024]
    const float *b_f, *b_i, *b_C, *b_o, *b_f1, *b_i1, *b_C1, *b_o1;
    unsigned* sync;          // bar0[16 lines], bar1[16], hcnt[16]; line = 32 uints
};

__global__ void __launch_bounds__(512, 2) persist_k(PArgs a) {
    extern __shared__ u16 lds[];
    u16* WL = lds;
    float (*red)[64][33] = (float (*)[64][33])(lds + LDS_W_U16);

    const int b   = blockIdx.x;
    const int ub  = b & 127;
    const int tid = threadIdx.x;
    const bool L0 = (b < 128);

    // stage this block's W slice into LDS (k-inner-8, 32 local cols)
    {
        const u16* Wsrc = L0 ? a.Wcat0 : a.Wcat1;
        const int  kgs  = L0 ? 192 : 256;
        for (int i2 = tid; i2 < kgs * 32; i2 += 512) {
            const int kg = i2 >> 5, cc2 = i2 & 31;
            *(short8*)(WL + ((size_t)(kg * 32 + cc2)) * 8) =
                *(const short8*)(Wsrc + ((size_t)kg * NG + ub * 32 + cc2) * 8);
        }
    }

    // per-thread wave geometry (fixed across ticks)
    const int w = tid >> 6, l = tid & 63;
    const int ml = l & 15, q = l >> 4;
    const int km = w & 1, mw = w >> 1;
    const int row = mw * 16 + ml;

    // per-thread epilogue state
    const int ug = ub * 8 + (tid & 7);
    const float bF = L0 ? a.b_f[ug] : a.b_f1[ug];
    const float bI = L0 ? a.b_i[ug] : a.b_i1[ug];
    const float bC = L0 ? a.b_C[ug] : a.b_C1[ug];
    const float bO = L0 ? a.b_o[ug] : a.b_o1[ug];
    float c = 0.f;

    unsigned* bar0 = a.sync;               // 16 lines x 32 uints
    unsigned* bar1 = a.sync + 512;
    unsigned* hcnt = a.sync + 1024;
    const int lane16 = (ub & 15) * 32;     // this block's arrive line
    __syncthreads();                       // W staged (full barrier: lgkm drain)

    if (L0) {
        for (int t = 0; t < 128; ++t) {
            short8 areg[24];
            const u16* Xt = a.E + (size_t)t * BATCH * EMB;

            // 1) pre-issue E loads (km==0 waves: k = 0..511) — gate-free
            if (km == 0) {
                const u16* xb = Xt + (size_t)row * 512 + q * 8;
#pragma unroll
                for (int ci = 0; ci < 16; ++ci)
                    areg[ci] = *(const short8*)(xb + ci * 32);
            }
            // 2) wait previous-tick barrier (pollers = wave 1, km=1: no
            //    outstanding loads, so the poll's vmcnt drain is free)
            if (t > 0) {
                if (tid >= 64 && tid < 80)
                    wait_ge(bar0 + (tid - 64) * 32, 8u * (unsigned)t);
            }
            asm volatile("" ::: "memory");
            __builtin_amdgcn_s_barrier();          // control-only join
            // 3) issue h loads (h0c[t] now fully written)
            const u16* hin = a.h0c + (size_t)t * BH;
            {
                const u16* hb = hin + (size_t)row * HID + q * 8;
                if (km == 0) {
#pragma unroll
                    for (int ci = 16; ci < 24; ++ci)
                        areg[ci] = *(const short8*)(hb + (ci * 32 - 512));
                } else {
#pragma unroll
                    for (int ci = 0; ci < 24; ++ci)
                        areg[ci] = *(const short8*)(hb + 256 + ci * 32);
                }
            }
            // 4) compute
            u16* ho = a.h0c + (size_t)(t + 1) * BH;
            step_compute<24, true>(WL, red, areg, ho, a.H + (size_t)t * BH,
                                   c, bF, bI, bC, bO, ub);
            asm volatile("s_waitcnt vmcnt(0)" ::: "memory");  // stores at L3
            __syncthreads();
            if (tid == 0) {
                __hip_atomic_fetch_add(hcnt + lane16, 1u, __ATOMIC_RELAXED, __HIP_MEMORY_SCOPE_AGENT);
                __hip_atomic_fetch_add(bar0 + lane16, 1u, __ATOMIC_RELAXED, __HIP_MEMORY_SCOPE_AGENT);
            }
        }
    } else {
        for (int s = 0; s < 128; ++s) {
            short8 areg[32];
            // 1) wait own-layer prev tick (h1c[s] complete) — early signal
            if (s > 0) {
                if (tid < 16) wait_ge(bar1 + tid * 32, 8u * (unsigned)s);
                asm volatile("" ::: "memory");
                __builtin_amdgcn_s_barrier();      // control-only join
            }
            // 2) km==1 waves issue h1 loads now (fly during the hcnt wait)
            const u16* hin = a.h1c + (size_t)s * BH;
            if (km == 1) {
                const u16* hb = hin + (size_t)row * HID + q * 8;
#pragma unroll
                for (int ci = 0; ci < 32; ++ci)
                    areg[ci] = *(const short8*)(hb + ci * 32);
            }
            // 3) wait L0 produced H[s] (pollers = wave 0, km=0: no
            //    outstanding loads of their own)
            if (tid < 16) wait_ge(hcnt + tid * 32, 8u * (unsigned)(s + 1));
            asm volatile("" ::: "memory");
            __builtin_amdgcn_s_barrier();          // control-only join
            // 4) km==0 waves issue H[s] loads
            const u16* Xt = a.H + (size_t)s * BH;
            if (km == 0) {
                const u16* xb = Xt + (size_t)row * HID + q * 8;
#pragma unroll
                for (int ci = 0; ci < 32; ++ci)
                    areg[ci] = *(const short8*)(xb + ci * 32);
            }
            // 5) compute
            u16* ho = a.h1c + (size_t)(s + 1) * BH;
            step_compute<32, false>(WL, red, areg, ho, nullptr,
                                    c, bF, bI, bC, bO, ub);
            asm volatile("s_waitcnt vmcnt(0)" ::: "memory");
            __syncthreads();
            if (tid == 0)
                __hip_atomic_fetch_add(bar1 + lane16, 1u, __ATOMIC_RELAXED, __HIP_MEMORY_SCOPE_AGENT);
        }
    }
    // final h1 = h1c + 128*BH; out_gemm is a separate launch (boundary coherence)
}

// out[64][10000] = h1 @ W_out + b_out   (314 blocks x 32 cols) — round-1 verified
__global__ void __launch_bounds__(256) out_gemm(
    const u16* __restrict__ h1, const u16* __restrict__ W,
    const float* __restrict__ bout, float* __restrict__ out)
{
    __shared__ float red[4][64][33];
    const int tid = threadIdx.x;
    const int w = tid >> 6, l = tid & 63;
    const int ml = l & 15, q = l >> 4;
    const int n0 = blockIdx.x * 32;

    floatx4 acc[4][2];
#pragma unroll
    for (int mi = 0; mi < 4; ++mi)
#pragma unroll
        for (int ni = 0; ni < 2; ++ni)
            acc[mi][ni] = (floatx4){0.f, 0.f, 0.f, 0.f};

#pragma unroll
    for (int ci = 0; ci < 8; ++ci) {
        const int k = (ci * 4 + w) << 5;
        const u16* ar = h1 + (size_t)ml * HID + k + q * 8;
        short8 a0 = *(const short8*)(ar);
        short8 a1 = *(const short8*)(ar + 16 * HID);
        short8 a2 = *(const short8*)(ar + 32 * HID);
        short8 a3 = *(const short8*)(ar + 48 * HID);
        const u16* br = W + ((size_t)((k >> 3) + q) * NOP + n0 + ml) * 8;
        short8 b0 = *(const short8*)(br);
        short8 b1 = *(const short8*)(br + 16 * 8);
        acc[0][0] = __builtin_amdgcn_mfma_f32_16x16x32_bf16(a0, b0, acc[0][0], 0, 0, 0);
        acc[1][0] = __builtin_amdgcn_mfma_f32_16x16x32_bf16(a1, b0, acc[1][0], 0, 0, 0);
        acc[2][0] = __builtin_amdgcn_mfma_f32_16x16x32_bf16(a2, b0, acc[2][0], 0, 0, 0);
        acc[3][0] = __builtin_amdgcn_mfma_f32_16x16x32_bf16(a3, b0, acc[3][0], 0, 0, 0);
        acc[0][1] = __builtin_amdgcn_mfma_f32_16x16x32_bf16(a0, b1, acc[0][1], 0, 0, 0);
        acc[1][1] = __builtin_amdgcn_mfma_f32_16x16x32_bf16(a1, b1, acc[1][1], 0, 0, 0);
        acc[2][1] = __builtin_amdgcn_mfma_f32_16x16x32_bf16(a2, b1, acc[2][1], 0, 0, 0);
        acc[3][1] = __builtin_amdgcn_mfma_f32_16x16x32_bf16(a3, b1, acc[3][1], 0, 0, 0);
    }

#pragma unroll
    for (int mi = 0; mi < 4; ++mi)
#pragma unroll
        for (int ni = 0; ni < 2; ++ni)
#pragma unroll
            for (int r = 0; r < 4; ++r)
                red[w][mi * 16 + q * 4 + r][ni * 16 + ml] = acc[mi][ni][r];
    __syncthreads();

    const int m = tid >> 2;
#pragma unroll
    for (int jj = 0; jj < 8; ++jj) {
        const int nl = (tid & 3) * 8 + jj;
        const int n = n0 + nl;
        if (n < NCLS) {
            float v = red[0][m][nl] + red[1][m][nl] + red[2][m][nl] + red[3][m][nl] + bout[n];
            out[(size_t)m * NCLS + n] = v;
        }
    }
}

// ---------------------------------------------------------------------------
extern "C" void kernel_launch(void* const* d_in, const int* in_sizes, int n_in,
                              void* d_out, int out_size, void* d_ws, size_t ws_size,
                              hipStream_t stream) {
    (void)in_sizes; (void)n_in; (void)out_size; (void)ws_size;
    const int*   X     = (const int*)  d_in[0];
    const float* C     = (const float*)d_in[1];
    const float* W_fx  = (const float*)d_in[2];
    const float* W_fh  = (const float*)d_in[3];
    const float* W_ix  = (const float*)d_in[4];
    const float* W_ih  = (const float*)d_in[5];
    const float* W_Cx  = (const float*)d_in[6];
    const float* W_Ch  = (const float*)d_in[7];
    const float* W_ox  = (const float*)d_in[8];
    const float* W_oh  = (const float*)d_in[9];
    const float* W_fx1 = (const float*)d_in[10];
    const float* W_fh1 = (const float*)d_in[11];
    const float* W_ix1 = (const float*)d_in[12];
    // d_in[13] = W_ih1 — unused: reference reuses W_ih in layer-1 i-gate (bug kept)
    const float* W_Cx1 = (const float*)d_in[14];
    const float* W_Ch1 = (const float*)d_in[15];
    const float* W_ox1 = (const float*)d_in[16];
    const float* W_oh1 = (const float*)d_in[17];
    const float* W_out = (const float*)d_in[18];
    const float* b_f   = (const float*)d_in[19];
    const float* b_i   = (const float*)d_in[20];
    const float* b_C   = (const float*)d_in[21];
    const float* b_o   = (const float*)d_in[22];
    const float* b_f1  = (const float*)d_in[23];
    const float* b_i1  = (const float*)d_in[24];
    const float* b_C1  = (const float*)d_in[25];
    const float* b_o1  = (const float*)d_in[26];
    const float* b_out = (const float*)d_in[27];
    float* out = (float*)d_out;

    // workspace carve (~105 MB)
    uint8_t* ws = (uint8_t*)d_ws;
    const size_t SZ_WCAT0 = (size_t)1536 * NG * 2;      // 12 MB
    const size_t SZ_WCAT1 = (size_t)2048 * NG * 2;      // 16 MB
    const size_t SZ_WOUTP = (size_t)1024 * NOP * 2;     // ~20 MB
    const size_t SZ_E     = (size_t)SEQ * BATCH * EMB * 2;    // 8 MB
    const size_t SZ_H     = (size_t)SEQ * BH * 2;             // 16 MB
    const size_t SZ_HC    = (size_t)(SEQ + 1) * BH * 2;       // 16.6 MB per chain
    u16*   Wcat0 = (u16*)ws;                         ws += SZ_WCAT0;
    u16*   Wcat1 = (u16*)ws;                         ws += SZ_WCAT1;
    u16*   WoutP = (u16*)ws;                         ws += SZ_WOUTP;
    u16*   E     = (u16*)ws;                         ws += SZ_E;
    u16*   H     = (u16*)ws;                         ws += SZ_H;
    u16*   h0c   = (u16*)ws;                         ws += SZ_HC;
    u16*   h1c   = (u16*)ws;                         ws += SZ_HC;
    unsigned* syncw = (unsigned*)ws;                 ws += 8192;

    // allow 147968 B dynamic LDS (host-side, capture-safe; validated round 3/5)
    hipFuncSetAttribute((const void*)persist_k,
                        hipFuncAttributeMaxDynamicSharedMemorySize, LDS_BYTES);

    // --- pack weights + embed (parallel prep work)
    pack_gates<<<256, 256, 0, stream>>>(W_fx, W_ix, W_Cx, W_ox, Wcat0, 64, 0);
    pack_gates<<<512, 256, 0, stream>>>(W_fh, W_ih, W_Ch, W_oh, Wcat0, 128, 64);
    pack_gates<<<512, 256, 0, stream>>>(W_fx1, W_ix1, W_Cx1, W_ox1, Wcat1, 128, 0);
    pack_gates<<<512, 256, 0, stream>>>(W_fh1, W_ih, W_Ch1, W_oh1, Wcat1, 128, 128);
    hipMemsetAsync(WoutP, 0, SZ_WOUTP, stream);
    pack_wout<<<(128 * NCLS + 255) / 256, 256, 0, stream>>>(W_out, WoutP);
    embed_k<<<SEQ * BATCH, 128, 0, stream>>>(X, C, E);

    // --- zero slot 0 of both h chains + sync counters
    hipMemsetAsync(h0c, 0, (size_t)BH * 2, stream);
    hipMemsetAsync(h1c, 0, (size_t)BH * 2, stream);
    hipMemsetAsync(syncw, 0, 8192, stream);

    // --- the whole recurrence in one launch
    PArgs pa;
    pa.E = E; pa.Wcat0 = Wcat0; pa.Wcat1 = Wcat1;
    pa.H = H; pa.h0c = h0c; pa.h1c = h1c;
    pa.b_f = b_f; pa.b_i = b_i; pa.b_C = b_C; pa.b_o = b_o;
    pa.b_f1 = b_f1; pa.b_i1 = b_i1; pa.b_C1 = b_C1; pa.b_o1 = b_o1;
    pa.sync = syncw;
    persist_k<<<256, 512, LDS_BYTES, stream>>>(pa);

    // --- output projection (kernel boundary = full coherence for h1c final slot)
    out_gemm<<<314, 256, 0, stream>>>(h1c + (size_t)SEQ * BH, WoutP, b_out, out);
}